// Round 8
// baseline (310.656 us; speedup 1.0000x reference)
//
#include <hip/hip_runtime.h>
#include <hip/hip_bf16.h>

typedef __hip_bfloat16 bf16;
typedef __attribute__((ext_vector_type(8))) __bf16 bf16x8;
typedef __attribute__((ext_vector_type(4))) float f32x4;

#define BB 8
#define NN 8192
#define DIM 256
#define HEAD 4
#define HD 64
#define RANK 64
#define BN (BB*NN)

__device__ __forceinline__ float b2f(bf16 v){ return __bfloat162float(v); }
__device__ __forceinline__ bf16 f2b(float v){ return __float2bfloat16(v); }
__device__ __forceinline__ unsigned short f2bu(float f){
    bf16 h = __float2bfloat16(f);
    return *(unsigned short*)&h;
}
__device__ __forceinline__ float u2f(unsigned short u){
    unsigned int x = ((unsigned int)u) << 16; return __uint_as_float(x);
}
__device__ __forceinline__ __bf16 f2bb(float f){
    bf16 h = __float2bfloat16(f);
    return *reinterpret_cast<__bf16*>(&h);
}
// physical position of (outer, k) in a chunk-swizzled [outer][K] bf16 LDS tile
__device__ __forceinline__ int swz(int k, int outer){
    return (((k >> 3) ^ (outer & 7)) << 3) | (k & 7);
}

// ---------------------------------------------------------------------------
// kW: precompute WattnT[c][f] (K folded, /8 folded), WvT[c][f], battn[c].
//     Also zeroes pooledT (replaces the hipMemsetAsync dispatch).
// ---------------------------------------------------------------------------
__global__ void __launch_bounds__(256) kW(
    const float* __restrict__ Wq, const float* __restrict__ bq,
    const float* __restrict__ Km, const float* __restrict__ Wv,
    unsigned short* __restrict__ WattnT, unsigned short* __restrict__ WvT,
    float* __restrict__ battn, float* __restrict__ pooledZ)
{
    const int c = blockIdx.x;       // output col = h*64+r
    const int h = c >> 6, r = c & 63;
    const int t = threadIdx.x;      // f

    // zero pooledT: 131072 floats / 65536 threads = 2 per thread
    {
        int idx = (blockIdx.x*256 + t)*2;
        *(float2*)&pooledZ[idx] = (float2){0.f, 0.f};
    }

    __shared__ float Ks[64];
    if(t < 64) Ks[t] = Km[((size_t)r*HEAD + h)*64 + t];
    __syncthreads();

    const float* wqrow = Wq + (size_t)t*DIM + h*64;
    float a = 0.f;
    #pragma unroll
    for(int d = 0; d < 64; d++) a = fmaf(wqrow[d], Ks[d], a);
    WattnT[(size_t)c*DIM + t] = f2bu(0.125f * a);
    WvT[(size_t)c*DIM + t]    = f2bu(Wv[(size_t)t*DIM + c]);
    if(t == 0){
        float bb = 0.f;
        for(int d = 0; d < 64; d++) bb += bq[h*64+d]*Ks[d];
        battn[c] = 0.125f * bb;
    }
}

// ---------------------------------------------------------------------------
// kG: merged GEMM dispatch, 2048 blocks. role = blockIdx.x & 1:
//   role 0: xv  = x @ WvT^T + bv        -> fp32 outF
//   role 1: attn = z @ WattnT^T + battn -> bf16 attn + col stats Pm/Ps
// Single-barrier structure (r6-verified, 95 us).
// ---------------------------------------------------------------------------
__global__ void __launch_bounds__(256) kG(
    const float* __restrict__ x, const float* __restrict__ z,
    const unsigned short* __restrict__ WvT, const unsigned short* __restrict__ WattnT,
    const float* __restrict__ bv, const float* __restrict__ battn,
    float* __restrict__ outF, unsigned short* __restrict__ outB,
    float* __restrict__ Pm, float* __restrict__ Ps)
{
    __shared__ __attribute__((aligned(16))) __bf16 As8[8][64][40];  // 40 KB

    const int role = blockIdx.x & 1;
    const int tile = blockIdx.x >> 1;

    const float* A            = role ? z : x;
    const unsigned short* WT  = role ? WattnT : WvT;
    const float* bias         = role ? battn : bv;

    const int t    = threadIdx.x;
    const int lane = t & 63;
    const int w    = t >> 6;
    const int q    = lane >> 4;
    const int l15  = lane & 15;
    const int brow = tile * 64;
    const int arow = t >> 2, aseg = t & 3;

    const float* aSrc = A + (size_t)(brow + arow)*DIM + aseg*8;
    const unsigned short* bBase = WT + (size_t)(w*64 + l15)*DIM + q*8;

    // ---- B prefetch depth 2: steps 0 and 1 issued before staging ----
    bf16x8 b0[4], b1[4];
    #pragma unroll
    for(int tn = 0; tn < 4; tn++)
        b0[tn] = *(const bf16x8*)(bBase + (size_t)tn*16*DIM);
    #pragma unroll
    for(int tn = 0; tn < 4; tn++)
        b1[tn] = *(const bf16x8*)(bBase + (size_t)tn*16*DIM + 32);

    // ---- stage the whole A tile: 8 slabs, 2 float4 loads each ----
    #pragma unroll
    for(int s = 0; s < 8; s++){
        float4 v0 = *(const float4*)(aSrc + s*32);
        float4 v1 = *(const float4*)(aSrc + s*32 + 4);
        __attribute__((aligned(16))) __bf16 tmp[8] = {
            f2bb(v0.x), f2bb(v0.y), f2bb(v0.z), f2bb(v0.w),
            f2bb(v1.x), f2bb(v1.y), f2bb(v1.z), f2bb(v1.w)};
        *(bf16x8*)&As8[s][arow][aseg*8] = *(bf16x8*)tmp;
    }

    f32x4 acc[4][4];
    #pragma unroll
    for(int tm = 0; tm < 4; tm++)
        #pragma unroll
        for(int tn = 0; tn < 4; tn++) acc[tm][tn] = (f32x4){0.f,0.f,0.f,0.f};

    __syncthreads();   // the ONLY barrier

    #pragma unroll
    for(int step = 0; step < 8; step++){
        bf16x8 b2[4];
        if(step < 6){
            #pragma unroll
            for(int tn = 0; tn < 4; tn++)
                b2[tn] = *(const bf16x8*)(bBase + (size_t)tn*16*DIM + (step+2)*32);
        }

        bf16x8 af[4];
        #pragma unroll
        for(int tm = 0; tm < 4; tm++)
            af[tm] = *(const bf16x8*)&As8[step][tm*16 + l15][q*8];

        #pragma unroll
        for(int tm = 0; tm < 4; tm++)
            #pragma unroll
            for(int tn = 0; tn < 4; tn++)
                acc[tm][tn] = __builtin_amdgcn_mfma_f32_16x16x32_bf16(
                    af[tm], b0[tn], acc[tm][tn], 0, 0, 0);

        #pragma unroll
        for(int tn = 0; tn < 4; tn++){ b0[tn] = b1[tn]; b1[tn] = b2[tn]; }
    }

    if(role){
        const int b  = brow >> 13;
        const int nb = brow & 8191;
        const size_t blk = tile;
        #pragma unroll
        for(int tn = 0; tn < 4; tn++){
            int col = w*64 + tn*16 + l15;
            int hh = col >> 6, rr = col & 63;
            float bcol = bias[col];
            float rv[16];
            float m16 = -1e30f;
            #pragma unroll
            for(int tm = 0; tm < 4; tm++){
                #pragma unroll
                for(int reg = 0; reg < 4; reg++){
                    float v = acc[tm][tn][reg] + bcol;
                    unsigned short ub = f2bu(v);
                    int n = nb + tm*16 + q*4 + reg;
                    outB[(((size_t)(b*HEAD + hh))*NN + n)*64 + rr] = ub;
                    float vr = u2f(ub);
                    rv[tm*4+reg] = vr;
                    m16 = fmaxf(m16, vr);
                }
            }
            float s16 = 0.f;
            #pragma unroll
            for(int i = 0; i < 16; i++) s16 += __expf(rv[i] - m16);
            #pragma unroll
            for(int off = 16; off <= 32; off <<= 1){
                float m2 = __shfl_xor(m16, off, 64);
                float s2 = __shfl_xor(s16, off, 64);
                float nm = fmaxf(m16, m2);
                s16 = s16*__expf(m16-nm) + s2*__expf(m2-nm);
                m16 = nm;
            }
            if(q == 0){
                Pm[blk*256 + col] = m16;
                Ps[blk*256 + col] = s16;
            }
        }
    } else {
        #pragma unroll
        for(int tn = 0; tn < 4; tn++){
            int col = w*64 + tn*16 + l15;
            float bcol = bias[col];
            #pragma unroll
            for(int tm = 0; tm < 4; tm++){
                #pragma unroll
                for(int reg = 0; reg < 4; reg++){
                    int grow = brow + tm*16 + q*4 + reg;
                    outF[(size_t)grow*256 + col] = acc[tm][tn][reg] + bcol;
                }
            }
        }
    }
}

// ---------------------------------------------------------------------------
// kD: grid (32 bh, 16 cpair); each block handles chunks {2c, 2c+1} (256 rows
//   each). Chunk-1 attn loads are issued before chunk-0's barrier+MFMA so
//   HBM/L3 latency hides under compute (T14). xv loads overlap the exp pass.
//   Designated blocks (cpair==0 && bh%4==0) also fold the kC stat-merge.
// ---------------------------------------------------------------------------
__global__ void __launch_bounds__(256) kD(const unsigned short* __restrict__ attn,
                                          const float* __restrict__ xv,
                                          float* __restrict__ pooledT,
                                          const float* __restrict__ Pm, const float* __restrict__ Ps,
                                          float* __restrict__ Mst, float* __restrict__ Sst)
{
    __shared__ unsigned short s1T[64*256];  // [r][row] swizzled: raw exp(L - rowmax)
    __shared__ unsigned short xvT[64*256];  // [d][row] swizzled: xv / rowsum

    const int t = threadIdx.x, lane = t & 63, w = t >> 6;
    const int bh = blockIdx.x, cpair = blockIdx.y;
    const int b = bh >> 2, h = bh & 3;
    const int row = t;
    const int q = lane >> 4, l15 = lane & 15;

    // ---- folded kC: 8 designated blocks merge per-block stats ----
    if(cpair == 0 && (bh & 3) == 0){
        const int bb = bh >> 2, col = t;
        float m = -1e30f;
        for(int c = 0; c < 128; c++)
            m = fmaxf(m, Pm[(size_t)(bb*128 + c)*256 + col]);
        float s = 0.f;
        for(int c = 0; c < 128; c++){
            size_t i = (size_t)(bb*128 + c)*256 + col;
            s += Ps[i] * __expf(Pm[i] - m);
        }
        Mst[bb*256 + col] = m;
        Sst[bb*256 + col] = s;
    }

    // ---- prefetch chunk 0 attn row ----
    uint4 arA[8];
    {
        const uint4* ap = (const uint4*)(attn + ((size_t)bh*NN + cpair*512 + row)*64);
        #pragma unroll
        for(int c = 0; c < 8; c++) arA[c] = ap[c];
    }

    #pragma unroll 1
    for(int ci = 0; ci < 2; ci++){
        const int n0 = cpair*512 + ci*256;

        // ---- rowmax over r (unpack pass 1) ----
        float mx = -1e30f;
        #pragma unroll
        for(int c = 0; c < 8; c++){
            unsigned int uu[4] = {arA[c].x, arA[c].y, arA[c].z, arA[c].w};
            #pragma unroll
            for(int p = 0; p < 4; p++){
                mx = fmaxf(mx, __uint_as_float(uu[p] << 16));
                mx = fmaxf(mx, __uint_as_float(uu[p] & 0xffff0000u));
            }
        }
        // ---- issue xv loads (latency overlaps exp pass below) ----
        float4 xf[16];
        {
            const float4* xp = (const float4*)(xv + ((size_t)(b*NN + n0 + row))*256 + h*64);
            #pragma unroll
            for(int c = 0; c < 16; c++) xf[c] = xp[c];
        }
        // ---- exp pass + s1T staging (unpack pass 2) ----
        float s = 0.f;
        #pragma unroll
        for(int c = 0; c < 8; c++){
            unsigned int uu[4] = {arA[c].x, arA[c].y, arA[c].z, arA[c].w};
            #pragma unroll
            for(int p = 0; p < 4; p++){
                int r0 = c*8 + p*2;
                float e0 = __expf(__uint_as_float(uu[p] << 16)        - mx);
                float e1 = __expf(__uint_as_float(uu[p] & 0xffff0000u) - mx);
                s += e0 + e1;
                s1T[(r0+0)*256 + swz(row, r0+0)] = f2bu(e0);
                s1T[(r0+1)*256 + swz(row, r0+1)] = f2bu(e1);
            }
        }
        float rs = 1.f / s;
        #pragma unroll
        for(int c = 0; c < 16; c++){
            float4 f = xf[c];
            int d0 = c*4;
            xvT[(d0+0)*256 + swz(row, d0+0)] = f2bu(f.x * rs);
            xvT[(d0+1)*256 + swz(row, d0+1)] = f2bu(f.y * rs);
            xvT[(d0+2)*256 + swz(row, d0+2)] = f2bu(f.z * rs);
            xvT[(d0+3)*256 + swz(row, d0+3)] = f2bu(f.w * rs);
        }

        // ---- prefetch chunk 1 attn: in flight across barrier + MFMA ----
        if(ci == 0){
            const uint4* ap = (const uint4*)(attn + ((size_t)bh*NN + n0 + 256 + row)*64);
            #pragma unroll
            for(int c = 0; c < 8; c++) arA[c] = ap[c];
        }
        __syncthreads();

        // ---- MFMA pooledT[d][r] = sum_row xvT . s1T ----
        const int dm = w*16 + l15;   // a-frag outer (d)
        f32x4 acc[4];
        #pragma unroll
        for(int tn = 0; tn < 4; tn++) acc[tn] = (f32x4){0.f,0.f,0.f,0.f};

        #pragma unroll
        for(int slab = 0; slab < 8; slab++){
            int c = slab*4 + q;
            bf16x8 a = *(const bf16x8*)&xvT[dm*256 + ((c ^ (dm & 7))<<3)];
            #pragma unroll
            for(int tn = 0; tn < 4; tn++){
                int rn = tn*16 + l15;
                bf16x8 bb2 = *(const bf16x8*)&s1T[rn*256 + ((c ^ (rn & 7))<<3)];
                acc[tn] = __builtin_amdgcn_mfma_f32_16x16x32_bf16(a, bb2, acc[tn], 0, 0, 0);
            }
        }
        #pragma unroll
        for(int tn = 0; tn < 4; tn++){
            #pragma unroll
            for(int reg = 0; reg < 4; reg++){
                int d = w*16 + q*4 + reg;
                int r = tn*16 + l15;
                atomicAdd(&pooledT[((size_t)bh*64 + d)*64 + r], acc[tn][reg]);
            }
        }
        if(ci == 0) __syncthreads();   // LDS readers done before re-staging
    }
}

// ---------------------------------------------------------------------------
// kE: grid (32 bh, 16 cpair); each block handles chunks {2c, 2c+1}. plT and
//   Ms/Sinv staged once per block; chunk-1 attn loads issued before chunk-0's
//   barrier+MFMA (T14). out = sa*xv + sb*v.
// ---------------------------------------------------------------------------
__global__ void __launch_bounds__(256) kE(const unsigned short* __restrict__ attn,
                                          const float* __restrict__ xvin,
                                          const float* __restrict__ pooledT,
                                          const float* __restrict__ Mst, const float* __restrict__ Sst,
                                          const float* __restrict__ alpha, const float* __restrict__ beta,
                                          float* __restrict__ out)
{
    __shared__ unsigned short s2t[256*64];  // [row][r] swizzled
    __shared__ unsigned short plT[64*64];   // [d][r] swizzled
    __shared__ float Ms[64], Sinv[64];

    const int t = threadIdx.x, lane = t & 63, w = t >> 6;
    const int bh = blockIdx.x, cpair = blockIdx.y;
    const int b = bh >> 2, h = bh & 3;
    const int row = t;
    const int q = lane >> 4, l15 = lane & 15;

    if(t < 64){
        Ms[t]   = Mst[b*256 + h*64 + t];
        Sinv[t] = 1.f / Sst[b*256 + h*64 + t];
    }
    // stage pooledT -> bf16 LDS [d][r] (once; valid for both chunks)
    {
        int d = t >> 2, seg = t & 3;
        const float4* pp = (const float4*)(pooledT + ((size_t)bh*64 + d)*64 + seg*16);
        float4 p0 = pp[0], p1 = pp[1], p2 = pp[2], p3 = pp[3];
        __attribute__((aligned(16))) unsigned short tmp[16] = {
            f2bu(p0.x),f2bu(p0.y),f2bu(p0.z),f2bu(p0.w),
            f2bu(p1.x),f2bu(p1.y),f2bu(p1.z),f2bu(p1.w),
            f2bu(p2.x),f2bu(p2.y),f2bu(p2.z),f2bu(p2.w),
            f2bu(p3.x),f2bu(p3.y),f2bu(p3.z),f2bu(p3.w)};
        int c0 = seg*2;
        *(uint4*)&plT[d*64 + (((c0+0) ^ (d&7))<<3)] = *(uint4*)&tmp[0];
        *(uint4*)&plT[d*64 + (((c0+1) ^ (d&7))<<3)] = *(uint4*)&tmp[8];
    }

    // ---- prefetch chunk 0 attn row ----
    uint4 arA[8];
    {
        const uint4* ap = (const uint4*)(attn + ((size_t)bh*NN + cpair*512 + row)*64);
        #pragma unroll
        for(int c = 0; c < 8; c++) arA[c] = ap[c];
    }
    __syncthreads();   // Ms/Sinv + plT visible

    const float sa = 1.f / (1.f + __expf(-alpha[h]));
    const float sb = 1.f / (1.f + __expf(-beta[h]));

    #pragma unroll 1
    for(int ci = 0; ci < 2; ci++){
        const int n0 = cpair*512 + ci*256;

        // ---- s2 rows -> s2t ----
        #pragma unroll
        for(int c = 0; c < 8; c++){
            uint4 u = arA[c];
            unsigned int uu[4] = {u.x, u.y, u.z, u.w};
            unsigned int ov[4];
            #pragma unroll
            for(int p = 0; p < 4; p++){
                int r = c*8 + p*2;
                float v0 = __uint_as_float(uu[p] << 16);
                float v1 = __uint_as_float(uu[p] & 0xffff0000u);
                float e0 = __expf(v0 - Ms[r])   * Sinv[r];
                float e1 = __expf(v1 - Ms[r+1]) * Sinv[r+1];
                ov[p] = (unsigned int)f2bu(e0) | ((unsigned int)f2bu(e1) << 16);
            }
            uint4 w4; w4.x = ov[0]; w4.y = ov[1]; w4.z = ov[2]; w4.w = ov[3];
            *(uint4*)&s2t[row*64 + ((c ^ (row&7))<<3)] = w4;
        }

        // ---- prefetch chunk 1 attn: in flight across barrier + MFMA ----
        if(ci == 0){
            const uint4* ap = (const uint4*)(attn + ((size_t)bh*NN + n0 + 256 + row)*64);
            #pragma unroll
            for(int c = 0; c < 8; c++) arA[c] = ap[c];
        }
        __syncthreads();

        // ---- MFMA v[row][d] = sum_r s2t . plT ----
        f32x4 acc[4][4];
        #pragma unroll
        for(int tm = 0; tm < 4; tm++)
            #pragma unroll
            for(int tn = 0; tn < 4; tn++) acc[tm][tn] = (f32x4){0.f,0.f,0.f,0.f};

        #pragma unroll
        for(int s = 0; s < 2; s++){
            int c = s*4 + q;
            bf16x8 bfr[4], af[4];
            #pragma unroll
            for(int tn = 0; tn < 4; tn++){
                int dn = tn*16 + l15;
                bfr[tn] = *(const bf16x8*)&plT[dn*64 + ((c ^ (dn&7))<<3)];
            }
            #pragma unroll
            for(int tm = 0; tm < 4; tm++){
                int ra = w*64 + tm*16 + l15;
                af[tm] = *(const bf16x8*)&s2t[ra*64 + ((c ^ (ra&7))<<3)];
            }
            #pragma unroll
            for(int tm = 0; tm < 4; tm++)
                #pragma unroll
                for(int tn = 0; tn < 4; tn++)
                    acc[tm][tn] = __builtin_amdgcn_mfma_f32_16x16x32_bf16(
                        af[tm], bfr[tn], acc[tm][tn], 0, 0, 0);
        }

        #pragma unroll
        for(int tm = 0; tm < 4; tm++){
            #pragma unroll
            for(int reg = 0; reg < 4; reg++){
                int rowo = w*64 + tm*16 + q*4 + reg;
                size_t gbase = ((size_t)(b*NN + n0 + rowo))*256 + h*64;
                #pragma unroll
                for(int tn = 0; tn < 4; tn++){
                    int d = tn*16 + l15;
                    out[gbase + d] = sa*xvin[gbase + d] + sb*acc[tm][tn][reg];
                }
            }
        }
        if(ci == 0) __syncthreads();   // s2t readers done before re-staging
    }
}

extern "C" void kernel_launch(void* const* d_in, const int* in_sizes, int n_in,
                              void* d_out, int out_size, void* d_ws, size_t ws_size,
                              hipStream_t stream)
{
    (void)in_sizes; (void)n_in; (void)out_size; (void)ws_size;
    const float* x     = (const float*)d_in[0];
    const float* z     = (const float*)d_in[1];
    const float* Wq    = (const float*)d_in[2];
    const float* bq    = (const float*)d_in[3];
    const float* Km    = (const float*)d_in[4];
    const float* Wv    = (const float*)d_in[5];
    const float* bv    = (const float*)d_in[6];
    const float* alpha = (const float*)d_in[7];
    const float* beta  = (const float*)d_in[8];
    float* out = (float*)d_out;

    // xv fp32 lives in d_out: kG writes, kD/kE read, kE overwrites out[i]
    // in the same thread that read xv[i].
    float* xv = out;

    char* ws = (char*)d_ws;
    unsigned short* attn  = (unsigned short*)(ws + 0);         // 33,554,432 B  [b][h][n][r]
    float* pooledT = (float*)(ws + 33554432);                  // 524,288 B    [bh][d][r]
    float* Mst     = (float*)(ws + 34078720);                  // 8,192 B      [b][col]
    float* Sst     = (float*)(ws + 34086912);                  // 8,192 B
    float* Pm      = (float*)(ws + 34095104);                  // 1,048,576 B  [1024][256]
    float* Ps      = (float*)(ws + 35143680);                  // 1,048,576 B
    unsigned short* WattnT = (unsigned short*)(ws + 36192256); // 131,072 B
    unsigned short* WvT    = (unsigned short*)(ws + 36323328); // 131,072 B
    float* battn   = (float*)(ws + 36454400);                  // 1,024 B
                                                               // total: 36,455,424 B

    kW<<<dim3(256), 256, 0, stream>>>(Wq, bq, Km, Wv, WattnT, WvT, battn, pooledT);
    kG<<<dim3(2*BN/64), 256, 0, stream>>>(x, z, WvT, WattnT, bv, battn, xv, attn, Pm, Ps);
    kD<<<dim3(32, 16), 256, 0, stream>>>(attn, xv, pooledT, Pm, Ps, Mst, Sst);
    kE<<<dim3(32, 16), 256, 0, stream>>>(attn, xv, pooledT, Mst, Sst, alpha, beta, out);
}